// Round 10
// baseline (236.863 us; speedup 1.0000x reference)
//
#include <hip/hip_runtime.h>
#include <hip/hip_bf16.h>

// ChebConv K=4. out[b,v,o] = bias[o] + sum_{c<256} xs[c&3][v,(c>>2)*2+b] * Wflat[c*64+o]
// R20 = R19 + non-temporal hints on all single-use streaming accesses in the
// spmm kernels (epack reads, xprev reads, xout writes, A-panel reads, out
// writes). Mechanism (measured, R19 counters): spmm3f FETCH=98.8MB of which
// ~56MB is streaming traffic that write-allocates in the 4MiB/XCD L2 and
// evicts the randomly-gathered x rows (16x reuse each). nt -> no L2 allocate
// -> more L2 capacity for the gather working set. Gather loads stay cacheable.
// Everything else byte-identical to R19.

#define NV 50000
#define NE 800000
#define XROW 128       // elements per x row = 2 batches * 64 features
#define NROWS 100000
#define NTILES 6250    // NROWS / 16 == NV / 8
#define EPMAX 1600000  // >= NE + 15*NV (pad16 CSR upper bound)
#define BSHIFT 7
#define RPB 128        // rows per bucket
#define NB 391         // ceil(NV / RPB)
#define CAP 3072       // per-bucket tmp capacity (mean 2048, +22 sigma)
#define CHUNK 4096     // edges per bin1 block
#define P1_BLOCKS 196  // ceil(NE / CHUNK)
#define X0_BLOCKS 12500  // NV*64/256

using u16 = unsigned short;
using u32 = unsigned int;
using u64 = unsigned long long;
typedef __bf16 bf16x8 __attribute__((ext_vector_type(8)));
typedef float f32x4 __attribute__((ext_vector_type(4)));
typedef u32 u32x4 __attribute__((ext_vector_type(4)));

__device__ __forceinline__ float bflo(u32 g) { return __uint_as_float(g << 16); }
__device__ __forceinline__ float bfhi(u32 g) { return __uint_as_float(g & 0xffff0000u); }
__device__ __forceinline__ u32 pack_bf2(float a, float b) {
    u16 ha = __builtin_bit_cast(u16, (__bf16)a);
    u16 hb = __builtin_bit_cast(u16, (__bf16)b);
    return (u32)ha | ((u32)hb << 16);
}
__device__ __forceinline__ float unpack_f16hi(u32 rec) {
    u16 h = (u16)(rec >> 16);
    return (float)__builtin_bit_cast(_Float16, h);
}
__device__ __forceinline__ int pad16(int n) { return (n + 15) & ~15; }

// non-temporal 16B helpers (streaming, no L2 allocate)
__device__ __forceinline__ uint4 ntload4(const u32* p) {
    u32x4 t = __builtin_nontemporal_load((const u32x4*)p);
    return make_uint4(t[0], t[1], t[2], t[3]);
}
__device__ __forceinline__ void ntstore4(u32* p, uint4 v) {
    u32x4 t = {v.x, v.y, v.z, v.w};
    __builtin_nontemporal_store(t, (u32x4*)p);
}

// Pass 1: bin edges by row>>BSHIFT into fixed-capacity bucket slices of tmp.
__global__ __launch_bounds__(256) void bin1_k(const int* __restrict__ rows, const int* __restrict__ cols,
                                              const float* __restrict__ vals,
                                              int* __restrict__ binctr, u64* __restrict__ tmp) {
    __shared__ int bcnt[NB];
    __shared__ int bofs[NB];
    __shared__ int bcur[NB];
    __shared__ int gbase[NB];
    __shared__ int ps[256];
    __shared__ u64 stage[CHUNK];  // 32 KB
    int t = threadIdx.x;
    int base = blockIdx.x * CHUNK;
    int n = NE - base;
    if (n > CHUNK) n = CHUNK;
    if (n <= 0) return;

    for (int i = t; i < NB; i += 256) bcnt[i] = 0;
    __syncthreads();

    for (int i = t; i < n; i += 256) {
        atomicAdd(&bcnt[rows[base + i] >> BSHIFT], 1);
    }
    __syncthreads();

    int i0 = 2 * t, i1 = 2 * t + 1;
    int a0 = (i0 < NB) ? bcnt[i0] : 0;
    int a1 = (i1 < NB) ? bcnt[i1] : 0;
    ps[t] = a0 + a1;
    __syncthreads();
    for (int off = 1; off < 256; off <<= 1) {
        int v = (t >= off) ? ps[t - off] : 0;
        __syncthreads();
        ps[t] += v;
        __syncthreads();
    }
    int eb = ps[t] - (a0 + a1);
    if (i0 < NB) { bofs[i0] = eb;      bcur[i0] = eb;      gbase[i0] = i0 * CAP + atomicAdd(&binctr[i0], a0); }
    if (i1 < NB) { bofs[i1] = eb + a0; bcur[i1] = eb + a0; gbase[i1] = i1 * CAP + atomicAdd(&binctr[i1], a1); }
    __syncthreads();

    for (int i = t; i < n; i += 256) {
        int r = rows[base + i];
        int c = cols[base + i];
        u16 hv = __builtin_bit_cast(u16, (_Float16)vals[base + i]);
        u64 rec = ((u64)(u32)r << 32) | (u64)((u32)c | ((u32)hv << 16));
        int s = atomicAdd(&bcur[r >> BSHIFT], 1);
        stage[s] = rec;
    }
    __syncthreads();

    for (int i = t; i < n; i += 256) {
        u64 rec = stage[i];
        int b = (int)(rec >> (32 + BSHIFT));
        tmp[(size_t)(gbase[b] + (i - bofs[b]))] = rec;
    }
}

// Pass 2a: per-bucket row histogram -> rowc[], padded bucket total; last block scans.
__global__ __launch_bounds__(256) void bcnt_k(const u64* __restrict__ tmp, const int* __restrict__ binctr,
                                              int* __restrict__ rowc, int* __restrict__ btot,
                                              int* __restrict__ done,
                                              int* __restrict__ bbase, int* __restrict__ row_ptr) {
    __shared__ int rc[RPB];
    __shared__ int rs[RPB];
    __shared__ int ps[256];
    __shared__ int flag;
    int b = blockIdx.x, t = threadIdx.x;
    int n = binctr[b];
    const u64* rec = tmp + (size_t)b * CAP;
    if (t < RPB) rc[t] = 0;
    __syncthreads();
    for (int i = t; i < n; i += 256) {
        atomicAdd(&rc[(int)(rec[i] >> 32) & (RPB - 1)], 1);
    }
    __syncthreads();
    if (t < RPB) {
        rowc[b * RPB + t] = rc[t];
        rs[t] = pad16(rc[t]);
    }
    __syncthreads();
    for (int off = 64; off > 0; off >>= 1) {
        if (t < off) rs[t] += rs[t + off];
        __syncthreads();
    }
    if (t == 0) {
        btot[b] = rs[0];
        __threadfence();
        int ticket = atomicAdd(done, 1);
        flag = (ticket == NB - 1);
    }
    __syncthreads();
    if (flag) {
        __threadfence();
        int i0 = 2 * t, i1 = 2 * t + 1;
        int a0 = (i0 < NB) ? atomicAdd(&btot[i0], 0) : 0;  // coherent cross-XCD read
        int a1 = (i1 < NB) ? atomicAdd(&btot[i1], 0) : 0;
        ps[t] = a0 + a1;
        __syncthreads();
        for (int off = 1; off < 256; off <<= 1) {
            int v = (t >= off) ? ps[t - off] : 0;
            __syncthreads();
            ps[t] += v;
            __syncthreads();
        }
        int eb = ps[t] - (a0 + a1);
        if (i0 < NB) bbase[i0] = eb;
        if (i1 < NB) bbase[i1] = eb + a0;
        if (t == 255) row_ptr[NV] = ps[255];
    }
}

// Pass 2c: per bucket: row_ptr from LDS scan; place records; zero pad slots.
__global__ __launch_bounds__(256) void place_k(const u64* __restrict__ tmp, const int* __restrict__ binctr,
                                               const int* __restrict__ rowc, const int* __restrict__ bbase,
                                               int* __restrict__ row_ptr, u32* __restrict__ epack) {
    __shared__ int rc[RPB];
    __shared__ int ro[RPB];
    int b = blockIdx.x, t = threadIdx.x;
    int n = binctr[b];
    int base = bbase[b];
    const u64* rec = tmp + (size_t)b * CAP;

    int cv = (t < RPB) ? rowc[b * RPB + t] : 0;
    int pv = pad16(cv);
    if (t < RPB) ro[t] = pv;
    __syncthreads();
    for (int off = 1; off < RPB; off <<= 1) {
        int v = 0;
        if (t < RPB && t >= off) v = ro[t - off];
        __syncthreads();
        if (t < RPB) ro[t] += v;
        __syncthreads();
    }
    if (t < RPB) {
        int ex = ro[t] - pv;
        ro[t] = ex;
        rc[t] = 0;
        int v = (b << BSHIFT) + t;
        if (v < NV) row_ptr[v] = base + ex;
    }
    __syncthreads();
    for (int i = t; i < n; i += 256) {
        u64 r64 = rec[i];
        int r = (int)(r64 >> 32) & (RPB - 1);
        int p = base + ro[r] + atomicAdd(&rc[r], 1);
        epack[p] = (u32)r64;
    }
    __syncthreads();
    if (t < RPB) {
        int s = base + ro[t] + cv;
        int e = base + ro[t] + pv;
        for (int i = s; i < e; ++i) epack[i] = 0;
    }
}

// Merged: x0 build + weight image prep.
__global__ void bx0w_k(const float* __restrict__ in, u32* __restrict__ x0u,
                       const float* __restrict__ weight, u16* __restrict__ wimg) {
    int bid = blockIdx.x;
    if (bid < X0_BLOCKS) {
        int i = bid * 256 + threadIdx.x;  // uint index: v*64 + p
        int v = i >> 6, p = i & 63;
        int b = p >> 5;
        int f = (p & 31) * 2;
        const float* src = in + (size_t)b * (NV * 64) + (size_t)v * 64 + f;
        float2 t = *(const float2*)src;
        x0u[i] = pack_bf2(t.x, t.y);
    } else {
        int i = (bid - X0_BLOCKS) * 256 + threadIdx.x;
        int c = i >> 6, o = i & 63;
        int cp = ((c & 3) << 6) | (c >> 2);
        wimg[o * 264 + cp] = __builtin_bit_cast(u16, (__bf16)weight[i]);
    }
}

// Passes 1-2 spmm. Streaming accesses (epack, xprev, xout) are non-temporal;
// gather loads of x stay cacheable (16x reuse). mode 0: L x ; 1: 2 L x - xprev
__global__ __launch_bounds__(256) void spmm_k(const u32* __restrict__ x,
                                              const u32* __restrict__ xprev,
                                              const int* __restrict__ row_ptr,
                                              const u32* __restrict__ epack,
                                              u32* __restrict__ xout, int mode) {
    int wave = (int)((blockIdx.x * blockDim.x + threadIdx.x) >> 6);
    u32 lane = threadIdx.x & 63;
    int row = __builtin_amdgcn_readfirstlane(wave);
    if (row >= NV) return;
    int beg = row_ptr[row];
    int end = row_ptr[row + 1];
    int q = (int)(lane >> 4);
    u32 g16 = lane & 15;

    float ax[4] = {0.f, 0.f, 0.f, 0.f};
    float ay[4] = {0.f, 0.f, 0.f, 0.f};

    for (int e = beg; e < end; e += 16) {
        uint4 r4 = ntload4(epack + e + 4 * q);
        u32 rec[4] = {r4.x, r4.y, r4.z, r4.w};
        uint4 gv[4];
        #pragma unroll
        for (int u = 0; u < 4; ++u)
            gv[u] = *(const uint4*)(x + ((rec[u] & 0xffffu) << 6) + (g16 << 2));
        #pragma unroll
        for (int u = 0; u < 4; ++u) {
            float w = unpack_f16hi(rec[u]);
            ax[0] += w * bflo(gv[u].x); ay[0] += w * bfhi(gv[u].x);
            ax[1] += w * bflo(gv[u].y); ay[1] += w * bfhi(gv[u].y);
            ax[2] += w * bflo(gv[u].z); ay[2] += w * bfhi(gv[u].z);
            ax[3] += w * bflo(gv[u].w); ay[3] += w * bfhi(gv[u].w);
        }
    }

    #pragma unroll
    for (int m = 16; m <= 32; m <<= 1) {
        #pragma unroll
        for (int j = 0; j < 4; ++j) {
            ax[j] += __shfl_xor(ax[j], m, 64);
            ay[j] += __shfl_xor(ay[j], m, 64);
        }
    }

    if (q == 0) {
        if (mode) {
            uint4 pv = ntload4(xprev + ((u32)row << 6) + (g16 << 2));
            ax[0] = 2.f * ax[0] - bflo(pv.x); ay[0] = 2.f * ay[0] - bfhi(pv.x);
            ax[1] = 2.f * ax[1] - bflo(pv.y); ay[1] = 2.f * ay[1] - bfhi(pv.y);
            ax[2] = 2.f * ax[2] - bflo(pv.z); ay[2] = 2.f * ay[2] - bfhi(pv.z);
            ax[3] = 2.f * ax[3] - bflo(pv.w); ay[3] = 2.f * ay[3] - bfhi(pv.w);
        }
        uint4 o;
        o.x = pack_bf2(ax[0], ay[0]);
        o.y = pack_bf2(ax[1], ay[1]);
        o.z = pack_bf2(ax[2], ay[2]);
        o.w = pack_bf2(ax[3], ay[3]);
        ntstore4(xout + ((u32)row << 6) + (g16 << 2), o);
    }
}

// Fused pass-3 spmm + MFMA epilogue. One 512-thr block per 16-row tile (8 v).
// Streaming accesses (A-panel, epack, x1, out) non-temporal; x2 gathers cached.
__global__ __launch_bounds__(512) void spmm3f_k(const u32* __restrict__ x2,
                                                const u32* __restrict__ x1,
                                                const int* __restrict__ row_ptr,
                                                const u32* __restrict__ epack,
                                                const u16* __restrict__ x_all,
                                                const u16* __restrict__ wimg,
                                                const float* __restrict__ bias,
                                                float* __restrict__ out) {
    __shared__ u32 As[4 * 8 * 64];   // [arr][v'][16 units of 4 u32], unit ^= v'&7
    int t0 = blockIdx.x;
    int tid = threadIdx.x;
    int w = tid >> 6;
    u32 lane = tid & 63;

    // phase 0: cooperative stage of arrays 0-2 (1536 u32, 3 per thread), swizzled
    #pragma unroll
    for (int k = 0; k < 3; ++k) {
        int i = tid + k * 512;       // 0..1535
        int arr = i >> 9;            // 0..2
        int vp = (i >> 6) & 7;
        int c = i & 63;
        u32 val = __builtin_nontemporal_load(
            (const u32*)x_all + ((size_t)arr * NV + (size_t)(t0 * 8 + vp)) * 64 + c);
        int unit = (c >> 2) ^ (vp & 7);
        As[(arr * 8 + vp) * 64 + unit * 4 + (c & 3)] = val;
    }

    // phase 1: spmm for v = t0*8 + w  (x3 = 2 L x2 - x1)
    {
        int row = __builtin_amdgcn_readfirstlane(t0 * 8 + w);
        int beg = row_ptr[row];
        int end = row_ptr[row + 1];
        int q = (int)(lane >> 4);
        u32 g16 = lane & 15;

        float ax[4] = {0.f, 0.f, 0.f, 0.f};
        float ay[4] = {0.f, 0.f, 0.f, 0.f};

        for (int e = beg; e < end; e += 16) {
            uint4 r4 = ntload4(epack + e + 4 * q);
            u32 rec[4] = {r4.x, r4.y, r4.z, r4.w};
            uint4 gv[4];
            #pragma unroll
            for (int u = 0; u < 4; ++u)
                gv[u] = *(const uint4*)(x2 + ((rec[u] & 0xffffu) << 6) + (g16 << 2));
            #pragma unroll
            for (int u = 0; u < 4; ++u) {
                float wgt = unpack_f16hi(rec[u]);
                ax[0] += wgt * bflo(gv[u].x); ay[0] += wgt * bfhi(gv[u].x);
                ax[1] += wgt * bflo(gv[u].y); ay[1] += wgt * bfhi(gv[u].y);
                ax[2] += wgt * bflo(gv[u].z); ay[2] += wgt * bfhi(gv[u].z);
                ax[3] += wgt * bflo(gv[u].w); ay[3] += wgt * bfhi(gv[u].w);
            }
        }

        #pragma unroll
        for (int m = 16; m <= 32; m <<= 1) {
            #pragma unroll
            for (int j = 0; j < 4; ++j) {
                ax[j] += __shfl_xor(ax[j], m, 64);
                ay[j] += __shfl_xor(ay[j], m, 64);
            }
        }

        if (q == 0) {
            uint4 pv = ntload4(x1 + ((u32)row << 6) + (g16 << 2));
            ax[0] = 2.f * ax[0] - bflo(pv.x); ay[0] = 2.f * ay[0] - bfhi(pv.x);
            ax[1] = 2.f * ax[1] - bflo(pv.y); ay[1] = 2.f * ay[1] - bfhi(pv.y);
            ax[2] = 2.f * ax[2] - bflo(pv.z); ay[2] = 2.f * ay[2] - bfhi(pv.z);
            ax[3] = 2.f * ax[3] - bflo(pv.w); ay[3] = 2.f * ay[3] - bfhi(pv.w);
            int unit = (int)g16 ^ (w & 7);
            u32* dst = &As[(3 * 8 + w) * 64 + unit * 4];
            dst[0] = pack_bf2(ax[0], ay[0]);
            dst[1] = pack_bf2(ax[1], ay[1]);
            dst[2] = pack_bf2(ax[2], ay[2]);
            dst[3] = pack_bf2(ax[3], ay[3]);
        }
    }
    __syncthreads();

    // phase 2: MFMA (waves 0-3, j = w)
    if (w < 4) {
        int j = w;
        int m = (int)lane & 15;
        int q8 = ((int)lane >> 4) * 8;
        int vp = m >> 1;
        int b = m & 1;
        f32x4 acc = {0, 0, 0, 0};
        #pragma unroll
        for (int kb = 0; kb < 8; ++kb) {
            int arr = kb >> 1;
            int unit = (b * 8 + (kb & 1) * 4 + ((int)lane >> 4)) ^ (vp & 7);
            bf16x8 a = *(const bf16x8*)&As[(arr * 8 + vp) * 64 + unit * 4];
            bf16x8 bj = *(const bf16x8*)&wimg[(j * 16 + m) * 264 + kb * 32 + q8];
            acc = __builtin_amdgcn_mfma_f32_16x16x32_bf16(a, bj, acc, 0, 0, 0);
        }
        float bv = bias[j * 16 + m];
        int rbase = t0 * 16 + ((int)lane >> 4) * 4;
        #pragma unroll
        for (int reg = 0; reg < 4; ++reg) {
            int rr = rbase + reg;
            __builtin_nontemporal_store(acc[reg] + bv,
                out + (size_t)(rr & 1) * (NV * 64) + (size_t)(rr >> 1) * 64 + j * 16 + m);
        }
    }
}

extern "C" void kernel_launch(void* const* d_in, const int* in_sizes, int n_in,
                              void* d_out, int out_size, void* d_ws, size_t ws_size,
                              hipStream_t stream) {
    const float* inputs = (const float*)d_in[0];
    const float* weight = (const float*)d_in[1];
    const float* bias   = (const float*)d_in[2];
    const float* lapv   = (const float*)d_in[3];
    const int*   lrows  = (const int*)d_in[4];
    const int*   lcols  = (const int*)d_in[5];
    float* out = (float*)d_out;

    char* ws = (char*)d_ws;
    size_t o = 0;
    auto alloc = [&](size_t bytes) -> void* {
        void* p = ws + o;
        o += (bytes + 255) & ~(size_t)255;
        return p;
    };
    u16* x_all = (u16*)alloc((size_t)4 * NV * XROW * 2);  // x0..x3 (x3 slot unused now)
    u32* epack = (u32*)alloc((size_t)EPMAX * 4);
    u64* tmp   = (u64*)alloc((size_t)NB * CAP * 8);
    int* row_ptr = (int*)alloc((size_t)(NV + 1) * 4);
    int* binctr  = (int*)alloc((size_t)(NB + 1) * 4);     // +1: done counter
    int* btot    = (int*)alloc((size_t)NB * 4);
    int* bbase   = (int*)alloc((size_t)NB * 4);
    int* rowc    = (int*)alloc((size_t)NB * RPB * 4);
    u16* wimg = (u16*)alloc((size_t)64 * 264 * 2);
    (void)ws_size; (void)in_sizes; (void)n_in; (void)out_size;

    int* done = binctr + NB;

    u32* x0 = (u32*)(x_all + (size_t)0 * NV * XROW);
    u32* x1 = (u32*)(x_all + (size_t)1 * NV * XROW);
    u32* x2 = (u32*)(x_all + (size_t)2 * NV * XROW);

    hipMemsetAsync(binctr, 0, (size_t)(NB + 1) * 4, stream);
    bin1_k<<<P1_BLOCKS, 256, 0, stream>>>(lrows, lcols, lapv, binctr, tmp);
    bcnt_k<<<NB, 256, 0, stream>>>(tmp, binctr, rowc, btot, done, bbase, row_ptr);
    place_k<<<NB, 256, 0, stream>>>(tmp, binctr, rowc, bbase, row_ptr, epack);
    bx0w_k<<<X0_BLOCKS + 64, 256, 0, stream>>>(inputs, x0, weight, wimg);

    spmm_k<<<(NV + 3) / 4, 256, 0, stream>>>(x0, nullptr, row_ptr, epack, x1, 0);
    spmm_k<<<(NV + 3) / 4, 256, 0, stream>>>(x1, x0, row_ptr, epack, x2, 1);

    spmm3f_k<<<NTILES, 512, 0, stream>>>(x2, x1, row_ptr, epack, x_all, wimg, bias, out);
}

// Round 11
// 226.496 us; speedup vs baseline: 1.0458x; 1.0458x over previous
//
#include <hip/hip_runtime.h>
#include <hip/hip_bf16.h>

// ChebConv K=4. out[b,v,o] = bias[o] + sum_{c<256} xs[c&3][v,(c>>2)*2+b] * Wflat[c*64+o]
// R21 = exact revert to R19 (best measured: 230.76us). R20's non-temporal
// hints are removed: measured +18% on spmm3f with FETCH unchanged -> the
// L2-eviction theory was refuted; nt bypassed caches that were serving the
// streams cheaply. R19 structure:
//   - bucket-local CSR build (bin1 -> bcnt+scan -> place), pad16, zero global
//     atomics, epack pads zeroed in-kernel.
//   - merged x0-build + weight-image prep (bx0w_k).
//   - spmm passes 1-2: one wave/row, 16-slot/4-gather body, uint4 epack read.
//   - pass 3 fused with MFMA epilogue (spmm3f_k): x3 never touches global;
//     A-panel staged to LDS XOR-swizzled; B from L2-hot wimg.

#define NV 50000
#define NE 800000
#define XROW 128       // elements per x row = 2 batches * 64 features
#define NROWS 100000
#define NTILES 6250    // NROWS / 16 == NV / 8
#define EPMAX 1600000  // >= NE + 15*NV (pad16 CSR upper bound)
#define BSHIFT 7
#define RPB 128        // rows per bucket
#define NB 391         // ceil(NV / RPB)
#define CAP 3072       // per-bucket tmp capacity (mean 2048, +22 sigma)
#define CHUNK 4096     // edges per bin1 block
#define P1_BLOCKS 196  // ceil(NE / CHUNK)
#define X0_BLOCKS 12500  // NV*64/256

using u16 = unsigned short;
using u32 = unsigned int;
using u64 = unsigned long long;
typedef __bf16 bf16x8 __attribute__((ext_vector_type(8)));
typedef float f32x4 __attribute__((ext_vector_type(4)));

__device__ __forceinline__ float bflo(u32 g) { return __uint_as_float(g << 16); }
__device__ __forceinline__ float bfhi(u32 g) { return __uint_as_float(g & 0xffff0000u); }
__device__ __forceinline__ u32 pack_bf2(float a, float b) {
    u16 ha = __builtin_bit_cast(u16, (__bf16)a);
    u16 hb = __builtin_bit_cast(u16, (__bf16)b);
    return (u32)ha | ((u32)hb << 16);
}
__device__ __forceinline__ float unpack_f16hi(u32 rec) {
    u16 h = (u16)(rec >> 16);
    return (float)__builtin_bit_cast(_Float16, h);
}
__device__ __forceinline__ int pad16(int n) { return (n + 15) & ~15; }

// Pass 1: bin edges by row>>BSHIFT into fixed-capacity bucket slices of tmp.
__global__ __launch_bounds__(256) void bin1_k(const int* __restrict__ rows, const int* __restrict__ cols,
                                              const float* __restrict__ vals,
                                              int* __restrict__ binctr, u64* __restrict__ tmp) {
    __shared__ int bcnt[NB];
    __shared__ int bofs[NB];
    __shared__ int bcur[NB];
    __shared__ int gbase[NB];
    __shared__ int ps[256];
    __shared__ u64 stage[CHUNK];  // 32 KB
    int t = threadIdx.x;
    int base = blockIdx.x * CHUNK;
    int n = NE - base;
    if (n > CHUNK) n = CHUNK;
    if (n <= 0) return;

    for (int i = t; i < NB; i += 256) bcnt[i] = 0;
    __syncthreads();

    for (int i = t; i < n; i += 256) {
        atomicAdd(&bcnt[rows[base + i] >> BSHIFT], 1);
    }
    __syncthreads();

    int i0 = 2 * t, i1 = 2 * t + 1;
    int a0 = (i0 < NB) ? bcnt[i0] : 0;
    int a1 = (i1 < NB) ? bcnt[i1] : 0;
    ps[t] = a0 + a1;
    __syncthreads();
    for (int off = 1; off < 256; off <<= 1) {
        int v = (t >= off) ? ps[t - off] : 0;
        __syncthreads();
        ps[t] += v;
        __syncthreads();
    }
    int eb = ps[t] - (a0 + a1);
    if (i0 < NB) { bofs[i0] = eb;      bcur[i0] = eb;      gbase[i0] = i0 * CAP + atomicAdd(&binctr[i0], a0); }
    if (i1 < NB) { bofs[i1] = eb + a0; bcur[i1] = eb + a0; gbase[i1] = i1 * CAP + atomicAdd(&binctr[i1], a1); }
    __syncthreads();

    for (int i = t; i < n; i += 256) {
        int r = rows[base + i];
        int c = cols[base + i];
        u16 hv = __builtin_bit_cast(u16, (_Float16)vals[base + i]);
        u64 rec = ((u64)(u32)r << 32) | (u64)((u32)c | ((u32)hv << 16));
        int s = atomicAdd(&bcur[r >> BSHIFT], 1);
        stage[s] = rec;
    }
    __syncthreads();

    for (int i = t; i < n; i += 256) {
        u64 rec = stage[i];
        int b = (int)(rec >> (32 + BSHIFT));
        tmp[(size_t)(gbase[b] + (i - bofs[b]))] = rec;
    }
}

// Pass 2a: per-bucket row histogram -> rowc[], padded bucket total; last block scans.
__global__ __launch_bounds__(256) void bcnt_k(const u64* __restrict__ tmp, const int* __restrict__ binctr,
                                              int* __restrict__ rowc, int* __restrict__ btot,
                                              int* __restrict__ done,
                                              int* __restrict__ bbase, int* __restrict__ row_ptr) {
    __shared__ int rc[RPB];
    __shared__ int rs[RPB];
    __shared__ int ps[256];
    __shared__ int flag;
    int b = blockIdx.x, t = threadIdx.x;
    int n = binctr[b];
    const u64* rec = tmp + (size_t)b * CAP;
    if (t < RPB) rc[t] = 0;
    __syncthreads();
    for (int i = t; i < n; i += 256) {
        atomicAdd(&rc[(int)(rec[i] >> 32) & (RPB - 1)], 1);
    }
    __syncthreads();
    if (t < RPB) {
        rowc[b * RPB + t] = rc[t];
        rs[t] = pad16(rc[t]);
    }
    __syncthreads();
    for (int off = 64; off > 0; off >>= 1) {
        if (t < off) rs[t] += rs[t + off];
        __syncthreads();
    }
    if (t == 0) {
        btot[b] = rs[0];
        __threadfence();
        int ticket = atomicAdd(done, 1);
        flag = (ticket == NB - 1);
    }
    __syncthreads();
    if (flag) {
        __threadfence();
        int i0 = 2 * t, i1 = 2 * t + 1;
        int a0 = (i0 < NB) ? atomicAdd(&btot[i0], 0) : 0;  // coherent cross-XCD read
        int a1 = (i1 < NB) ? atomicAdd(&btot[i1], 0) : 0;
        ps[t] = a0 + a1;
        __syncthreads();
        for (int off = 1; off < 256; off <<= 1) {
            int v = (t >= off) ? ps[t - off] : 0;
            __syncthreads();
            ps[t] += v;
            __syncthreads();
        }
        int eb = ps[t] - (a0 + a1);
        if (i0 < NB) bbase[i0] = eb;
        if (i1 < NB) bbase[i1] = eb + a0;
        if (t == 255) row_ptr[NV] = ps[255];
    }
}

// Pass 2c: per bucket: row_ptr from LDS scan; place records; zero pad slots.
__global__ __launch_bounds__(256) void place_k(const u64* __restrict__ tmp, const int* __restrict__ binctr,
                                               const int* __restrict__ rowc, const int* __restrict__ bbase,
                                               int* __restrict__ row_ptr, u32* __restrict__ epack) {
    __shared__ int rc[RPB];
    __shared__ int ro[RPB];
    int b = blockIdx.x, t = threadIdx.x;
    int n = binctr[b];
    int base = bbase[b];
    const u64* rec = tmp + (size_t)b * CAP;

    int cv = (t < RPB) ? rowc[b * RPB + t] : 0;
    int pv = pad16(cv);
    if (t < RPB) ro[t] = pv;
    __syncthreads();
    for (int off = 1; off < RPB; off <<= 1) {
        int v = 0;
        if (t < RPB && t >= off) v = ro[t - off];
        __syncthreads();
        if (t < RPB) ro[t] += v;
        __syncthreads();
    }
    if (t < RPB) {
        int ex = ro[t] - pv;
        ro[t] = ex;
        rc[t] = 0;
        int v = (b << BSHIFT) + t;
        if (v < NV) row_ptr[v] = base + ex;
    }
    __syncthreads();
    for (int i = t; i < n; i += 256) {
        u64 r64 = rec[i];
        int r = (int)(r64 >> 32) & (RPB - 1);
        int p = base + ro[r] + atomicAdd(&rc[r], 1);
        epack[p] = (u32)r64;
    }
    __syncthreads();
    if (t < RPB) {
        int s = base + ro[t] + cv;
        int e = base + ro[t] + pv;
        for (int i = s; i < e; ++i) epack[i] = 0;
    }
}

// Merged: x0 build + weight image prep.
__global__ void bx0w_k(const float* __restrict__ in, u32* __restrict__ x0u,
                       const float* __restrict__ weight, u16* __restrict__ wimg) {
    int bid = blockIdx.x;
    if (bid < X0_BLOCKS) {
        int i = bid * 256 + threadIdx.x;  // uint index: v*64 + p
        int v = i >> 6, p = i & 63;
        int b = p >> 5;
        int f = (p & 31) * 2;
        const float* src = in + (size_t)b * (NV * 64) + (size_t)v * 64 + f;
        float2 t = *(const float2*)src;
        x0u[i] = pack_bf2(t.x, t.y);
    } else {
        int i = (bid - X0_BLOCKS) * 256 + threadIdx.x;
        int c = i >> 6, o = i & 63;
        int cp = ((c & 3) << 6) | (c >> 2);
        wimg[o * 264 + cp] = __builtin_bit_cast(u16, (__bf16)weight[i]);
    }
}

// Passes 1-2 spmm (R18/R19 body). mode 0: L x ; 1: 2 L x - xprev
__global__ __launch_bounds__(256) void spmm_k(const u32* __restrict__ x,
                                              const u32* __restrict__ xprev,
                                              const int* __restrict__ row_ptr,
                                              const u32* __restrict__ epack,
                                              u32* __restrict__ xout, int mode) {
    int wave = (int)((blockIdx.x * blockDim.x + threadIdx.x) >> 6);
    u32 lane = threadIdx.x & 63;
    int row = __builtin_amdgcn_readfirstlane(wave);
    if (row >= NV) return;
    int beg = row_ptr[row];
    int end = row_ptr[row + 1];
    int q = (int)(lane >> 4);
    u32 g16 = lane & 15;

    float ax[4] = {0.f, 0.f, 0.f, 0.f};
    float ay[4] = {0.f, 0.f, 0.f, 0.f};

    for (int e = beg; e < end; e += 16) {
        uint4 r4 = *(const uint4*)(epack + e + 4 * q);
        u32 rec[4] = {r4.x, r4.y, r4.z, r4.w};
        uint4 gv[4];
        #pragma unroll
        for (int u = 0; u < 4; ++u)
            gv[u] = *(const uint4*)(x + ((rec[u] & 0xffffu) << 6) + (g16 << 2));
        #pragma unroll
        for (int u = 0; u < 4; ++u) {
            float w = unpack_f16hi(rec[u]);
            ax[0] += w * bflo(gv[u].x); ay[0] += w * bfhi(gv[u].x);
            ax[1] += w * bflo(gv[u].y); ay[1] += w * bfhi(gv[u].y);
            ax[2] += w * bflo(gv[u].z); ay[2] += w * bfhi(gv[u].z);
            ax[3] += w * bflo(gv[u].w); ay[3] += w * bfhi(gv[u].w);
        }
    }

    #pragma unroll
    for (int m = 16; m <= 32; m <<= 1) {
        #pragma unroll
        for (int j = 0; j < 4; ++j) {
            ax[j] += __shfl_xor(ax[j], m, 64);
            ay[j] += __shfl_xor(ay[j], m, 64);
        }
    }

    if (q == 0) {
        if (mode) {
            uint4 pv = *(const uint4*)(xprev + ((u32)row << 6) + (g16 << 2));
            ax[0] = 2.f * ax[0] - bflo(pv.x); ay[0] = 2.f * ay[0] - bfhi(pv.x);
            ax[1] = 2.f * ax[1] - bflo(pv.y); ay[1] = 2.f * ay[1] - bfhi(pv.y);
            ax[2] = 2.f * ax[2] - bflo(pv.z); ay[2] = 2.f * ay[2] - bfhi(pv.z);
            ax[3] = 2.f * ax[3] - bflo(pv.w); ay[3] = 2.f * ay[3] - bfhi(pv.w);
        }
        uint4 o;
        o.x = pack_bf2(ax[0], ay[0]);
        o.y = pack_bf2(ax[1], ay[1]);
        o.z = pack_bf2(ax[2], ay[2]);
        o.w = pack_bf2(ax[3], ay[3]);
        *(uint4*)(xout + ((u32)row << 6) + (g16 << 2)) = o;
    }
}

// Fused pass-3 spmm + MFMA epilogue. One 512-thr block per 16-row tile (8 v).
// Phase 0: stage A-panel arrays 0-2 (6KB) to LDS, XOR unit-swizzled by v'&7.
// Phase 1: wave w computes x3 row for v = t0*8+w (2 L x2 - x1) -> LDS (arr 3).
// Phase 2: waves 0-3, j = wave: 8x mfma_16x16x32, A from LDS, B from wimg (L2).
__global__ __launch_bounds__(512) void spmm3f_k(const u32* __restrict__ x2,
                                                const u32* __restrict__ x1,
                                                const int* __restrict__ row_ptr,
                                                const u32* __restrict__ epack,
                                                const u16* __restrict__ x_all,
                                                const u16* __restrict__ wimg,
                                                const float* __restrict__ bias,
                                                float* __restrict__ out) {
    __shared__ u32 As[4 * 8 * 64];   // [arr][v'][16 units of 4 u32], unit ^= v'&7
    int t0 = blockIdx.x;
    int tid = threadIdx.x;
    int w = tid >> 6;
    u32 lane = tid & 63;

    // phase 0: cooperative stage of arrays 0-2 (1536 u32, 3 per thread), swizzled
    #pragma unroll
    for (int k = 0; k < 3; ++k) {
        int i = tid + k * 512;       // 0..1535
        int arr = i >> 9;            // 0..2
        int vp = (i >> 6) & 7;
        int c = i & 63;
        u32 val = *((const u32*)x_all + ((size_t)arr * NV + (size_t)(t0 * 8 + vp)) * 64 + c);
        int unit = (c >> 2) ^ (vp & 7);
        As[(arr * 8 + vp) * 64 + unit * 4 + (c & 3)] = val;
    }

    // phase 1: spmm for v = t0*8 + w  (x3 = 2 L x2 - x1)
    {
        int row = __builtin_amdgcn_readfirstlane(t0 * 8 + w);
        int beg = row_ptr[row];
        int end = row_ptr[row + 1];
        int q = (int)(lane >> 4);
        u32 g16 = lane & 15;

        float ax[4] = {0.f, 0.f, 0.f, 0.f};
        float ay[4] = {0.f, 0.f, 0.f, 0.f};

        for (int e = beg; e < end; e += 16) {
            uint4 r4 = *(const uint4*)(epack + e + 4 * q);
            u32 rec[4] = {r4.x, r4.y, r4.z, r4.w};
            uint4 gv[4];
            #pragma unroll
            for (int u = 0; u < 4; ++u)
                gv[u] = *(const uint4*)(x2 + ((rec[u] & 0xffffu) << 6) + (g16 << 2));
            #pragma unroll
            for (int u = 0; u < 4; ++u) {
                float wgt = unpack_f16hi(rec[u]);
                ax[0] += wgt * bflo(gv[u].x); ay[0] += wgt * bfhi(gv[u].x);
                ax[1] += wgt * bflo(gv[u].y); ay[1] += wgt * bfhi(gv[u].y);
                ax[2] += wgt * bflo(gv[u].z); ay[2] += wgt * bfhi(gv[u].z);
                ax[3] += wgt * bflo(gv[u].w); ay[3] += wgt * bfhi(gv[u].w);
            }
        }

        #pragma unroll
        for (int m = 16; m <= 32; m <<= 1) {
            #pragma unroll
            for (int j = 0; j < 4; ++j) {
                ax[j] += __shfl_xor(ax[j], m, 64);
                ay[j] += __shfl_xor(ay[j], m, 64);
            }
        }

        if (q == 0) {
            uint4 pv = *(const uint4*)(x1 + ((u32)row << 6) + (g16 << 2));
            ax[0] = 2.f * ax[0] - bflo(pv.x); ay[0] = 2.f * ay[0] - bfhi(pv.x);
            ax[1] = 2.f * ax[1] - bflo(pv.y); ay[1] = 2.f * ay[1] - bfhi(pv.y);
            ax[2] = 2.f * ax[2] - bflo(pv.z); ay[2] = 2.f * ay[2] - bfhi(pv.z);
            ax[3] = 2.f * ax[3] - bflo(pv.w); ay[3] = 2.f * ay[3] - bfhi(pv.w);
            int unit = (int)g16 ^ (w & 7);
            u32* dst = &As[(3 * 8 + w) * 64 + unit * 4];
            dst[0] = pack_bf2(ax[0], ay[0]);
            dst[1] = pack_bf2(ax[1], ay[1]);
            dst[2] = pack_bf2(ax[2], ay[2]);
            dst[3] = pack_bf2(ax[3], ay[3]);
        }
    }
    __syncthreads();

    // phase 2: MFMA (waves 0-3, j = w)
    if (w < 4) {
        int j = w;
        int m = (int)lane & 15;
        int q8 = ((int)lane >> 4) * 8;
        int vp = m >> 1;
        int b = m & 1;
        f32x4 acc = {0, 0, 0, 0};
        #pragma unroll
        for (int kb = 0; kb < 8; ++kb) {
            int arr = kb >> 1;
            int unit = (b * 8 + (kb & 1) * 4 + ((int)lane >> 4)) ^ (vp & 7);
            bf16x8 a = *(const bf16x8*)&As[(arr * 8 + vp) * 64 + unit * 4];
            bf16x8 bj = *(const bf16x8*)&wimg[(j * 16 + m) * 264 + kb * 32 + q8];
            acc = __builtin_amdgcn_mfma_f32_16x16x32_bf16(a, bj, acc, 0, 0, 0);
        }
        float bv = bias[j * 16 + m];
        int rbase = t0 * 16 + ((int)lane >> 4) * 4;
        #pragma unroll
        for (int reg = 0; reg < 4; ++reg) {
            int rr = rbase + reg;
            out[(size_t)(rr & 1) * (NV * 64) + (size_t)(rr >> 1) * 64 + j * 16 + m] = acc[reg] + bv;
        }
    }
}

extern "C" void kernel_launch(void* const* d_in, const int* in_sizes, int n_in,
                              void* d_out, int out_size, void* d_ws, size_t ws_size,
                              hipStream_t stream) {
    const float* inputs = (const float*)d_in[0];
    const float* weight = (const float*)d_in[1];
    const float* bias   = (const float*)d_in[2];
    const float* lapv   = (const float*)d_in[3];
    const int*   lrows  = (const int*)d_in[4];
    const int*   lcols  = (const int*)d_in[5];
    float* out = (float*)d_out;

    char* ws = (char*)d_ws;
    size_t o = 0;
    auto alloc = [&](size_t bytes) -> void* {
        void* p = ws + o;
        o += (bytes + 255) & ~(size_t)255;
        return p;
    };
    u16* x_all = (u16*)alloc((size_t)4 * NV * XROW * 2);  // x0..x3 (x3 slot unused now)
    u32* epack = (u32*)alloc((size_t)EPMAX * 4);
    u64* tmp   = (u64*)alloc((size_t)NB * CAP * 8);
    int* row_ptr = (int*)alloc((size_t)(NV + 1) * 4);
    int* binctr  = (int*)alloc((size_t)(NB + 1) * 4);     // +1: done counter
    int* btot    = (int*)alloc((size_t)NB * 4);
    int* bbase   = (int*)alloc((size_t)NB * 4);
    int* rowc    = (int*)alloc((size_t)NB * RPB * 4);
    u16* wimg = (u16*)alloc((size_t)64 * 264 * 2);
    (void)ws_size; (void)in_sizes; (void)n_in; (void)out_size;

    int* done = binctr + NB;

    u32* x0 = (u32*)(x_all + (size_t)0 * NV * XROW);
    u32* x1 = (u32*)(x_all + (size_t)1 * NV * XROW);
    u32* x2 = (u32*)(x_all + (size_t)2 * NV * XROW);

    hipMemsetAsync(binctr, 0, (size_t)(NB + 1) * 4, stream);
    bin1_k<<<P1_BLOCKS, 256, 0, stream>>>(lrows, lcols, lapv, binctr, tmp);
    bcnt_k<<<NB, 256, 0, stream>>>(tmp, binctr, rowc, btot, done, bbase, row_ptr);
    place_k<<<NB, 256, 0, stream>>>(tmp, binctr, rowc, bbase, row_ptr, epack);
    bx0w_k<<<X0_BLOCKS + 64, 256, 0, stream>>>(inputs, x0, weight, wimg);

    spmm_k<<<(NV + 3) / 4, 256, 0, stream>>>(x0, nullptr, row_ptr, epack, x1, 0);
    spmm_k<<<(NV + 3) / 4, 256, 0, stream>>>(x1, x0, row_ptr, epack, x2, 1);

    spmm3f_k<<<NTILES, 512, 0, stream>>>(x2, x1, row_ptr, epack, x_all, wimg, bias, out);
}